// Round 16
// baseline (681.151 us; speedup 1.0000x reference)
//
#include <hip/hip_runtime.h>
#include <math.h>

typedef unsigned long long u64;
typedef unsigned int u32;

#define N_TOK 16384
#define DIM   256
#define KCB   4096

// ---- workspace layout (bytes) ----
#define WS_ROWMIN   0         // u64[16384] = 131072
#define WS_COLMIN   131072    // u64[4096]  = 32768   (0xFF region: [0,163840))
#define WS_CNT      163840    // float[4096]
#define WS_CPART    180224    // float[256]
#define WS_TOTAL    181248    // float[1]
#define WS_FLAG     181252    // int[1]   (written by detect kernel)
#define WS_F2       181312    // float[16384]
#define WS_C2       246848    // float[4096]
#define WS_END      263232

// ---- d_out layout (float elements) ----
#define OUT_FEAT    0
#define OUT_ASSIGN  4194304
#define OUT_CLOSS   4210688
#define OUT_UPCT    4210689
#define OUT_COUNT   4210690
#define OUT_AVG     4214786
#define OUT_CB      4218882   // also reused as feat_sum scratch (zeroed first)

// (float)(1.0 - 0.99) as jnp computes it (f64 -> f32 weak scalar)
#define C_1MG 0.009999999776482582f

__device__ __forceinline__ u32 fkey(float d) {
    u32 u = __float_as_uint(d);
    return (u & 0x80000000u) ? ~u : (u | 0x80000000u);
}
__device__ __forceinline__ u64 u64min(u64 a, u64 b) { return a < b ? a : b; }
__device__ __forceinline__ u64 shflxor64(u64 v, int m) {
    int lo = __shfl_xor((int)(u32)(v & 0xFFFFFFFFULL), m, 64);
    int hi = __shfl_xor((int)(u32)(v >> 32), m, 64);
    return ((u64)(u32)hi << 32) | (u32)lo;
}
__device__ __forceinline__ bool read_mask(const void* mp, int flag, int n) {
    if (flag == 2) return ((const float*)mp)[n] != 0.0f;
    if (flag == 1) return ((const int*)mp)[n] != 0;
    return ((const unsigned char*)mp)[n] != 0;
}
// async global->LDS, 16B/lane; LDS dest is wave-uniform base (+lane*16 implicit)
__device__ __forceinline__ void gload_lds16(const void* g, void* l) {
    __builtin_amdgcn_global_load_lds((const __attribute__((address_space(1))) void*)g,
                                     (__attribute__((address_space(3))) void*)l,
                                     16, 0, 0);
}

// Detect mask storage layout: 0 = uint8, 1 = int32, 2 = float32
__global__ void k_detect(const void* __restrict__ mp, int* __restrict__ flag) {
    if (threadIdx.x == 0) {
        const u32* w = (const u32*)mp;
        bool allf = true, alli = true, any1 = false;
        for (int i = 0; i < 64; ++i) {
            u32 x = w[i];
            if (x != 0u && x != 0x3F800000u) allf = false;
            if (x == 0x3F800000u) any1 = true;
            if (x > 1u) alli = false;
        }
        *flag = (allf && any1) ? 2 : (alli ? 1 : 0);
    }
}

// f2[n] = mask ? ||f_n||^2 : +inf ;  c2[k] = ||c_k||^2
__global__ __launch_bounds__(256)
void k_norms(const float* __restrict__ F, const float* __restrict__ CB,
             const void* __restrict__ mp, const int* __restrict__ flagp,
             float* __restrict__ f2, float* __restrict__ c2) {
    __shared__ float red[4];
    const int b = blockIdx.x, d = threadIdx.x;
    const float* src = (b < N_TOK) ? (F + (size_t)b * DIM) : (CB + (size_t)(b - N_TOK) * DIM);
    float v = src[d];
    float s = v * v;
#pragma unroll
    for (int m = 32; m > 0; m >>= 1) s += __shfl_xor(s, m, 64);
    if ((d & 63) == 0) red[d >> 6] = s;
    __syncthreads();
    if (d == 0) {
        float tot = red[0] + red[1] + red[2] + red[3];
        if (b < N_TOK) {
            bool msk = read_mask(mp, *flagp, b);
            f2[b] = msk ? tot : __builtin_huge_valf();
        } else {
            c2[b - N_TOK] = tot;
        }
    }
}

// Fused distance GEMM + dual argmin. Exact fp32 fmaf chain (k-ascending) —
// same summation order as rounds 9/11/13 (absmax 0 vs numpy argmin).
// r13 skeleton (PASSED correctness) with A moved into WAVE-PRIVATE LDS:
//  - Wave w owns rows rowbase+w*8+i. Its 8 A-rows are staged into a private
//    1 KB LDS slot by a HALF-WAVE gload (l<32): program-order safe, no
//    cross-wave dependency. a-reads = single-address wave-uniform broadcast
//    (zero bank traffic, no swizzle, base+imm addressing).
//  - B staged exactly as r13 (linear dest, pre-swizzled source; lane reads at
//    the 8-cycle bank-BW floor via the ((l>>1)&3) slot swizzle).
//  - Counted-vmcnt ping-pong: STAGE(s+1) [3 loads] -> vmcnt(3) -> raw
//    s_barrier -> compute(s) -> raw s_barrier.
// Tile 64 rows x 256 cols; block 512 (8 waves); grid (256, 16). Lane l owns
// cols l + j*64 (j<4); acc 8x4 = 32 VGPR. LDS = B 32 KB + A 8 KB = 40 KB.
__global__ __launch_bounds__(512, 2)
void k_gemm(const float* __restrict__ F, const float* __restrict__ CB,
            const float* __restrict__ f2, const float* __restrict__ c2,
            u64* __restrict__ rowmin, u64* __restrict__ colmin) {
    __shared__ float Bs[2 * 256 * 16];     // 32 KB (2 half-buffers of 256x16)
    __shared__ float As[8 * 2 * 128];      // 8 KB  (8 waves x 2 bufs x 8x16)

    const int t = threadIdx.x;             // 0..511
    const int l = t & 63;
    const int wave = __builtin_amdgcn_readfirstlane(t >> 6);
    const int rowbase = blockIdx.x * 64;
    const int kbase = blockIdx.y * 256;

    float acc[8][4];
#pragma unroll
    for (int i = 0; i < 8; ++i)
#pragma unroll
        for (int j = 0; j < 4; ++j) acc[i][j] = 0.0f;

    // B staging (r13-proven): thread t stages rows br0 = t>>2 and 128+br0,
    // 16B at byte-col (t&3)*16, source pre-swizzled so the linear LDS image
    // equals the slot-swizzled one.
    const int br0 = t >> 2;
    const int br1 = 128 + br0;
    const int bc4 = (t & 3) << 2;
    const int sc0 = bc4 ^ (((br0 >> 1) & 3) << 2);
    const int sc1 = bc4 ^ (((br1 >> 1) & 3) << 2);
    const char* gB0 = (const char*)(CB + (size_t)(kbase + br0) * DIM + sc0);
    const char* gB1 = (const char*)(CB + (size_t)(kbase + br1) * DIM + sc1);
    char* BsB = (char*)Bs;

    // A staging: half-wave (l<32): lane l covers row wave*8 + (l>>2),
    // 16 B at float-col (l&3)*4. Linear LDS image [8 rows][16 floats].
    const char* gA = (const char*)(F + (size_t)(rowbase + wave * 8 + (l >> 2)) * DIM)
                     + (l & 3) * 16;
    char* wA = (char*)As + wave * 1024;    // this wave's 1 KB (2 bufs x 512 B)

    const int bsw = ((l >> 1) & 3) << 2;   // b-read swizzle (uniform over j)

#define STAGE(s)                                                           \
    {                                                                      \
        const int boff_ = (((s) & 1) ? 16384 : 0) + wave * 1024;           \
        gload_lds16(gB0 + (s) * 64, BsB + boff_);                          \
        gload_lds16(gB1 + (s) * 64, BsB + 8192 + boff_);                   \
        if (l < 32) gload_lds16(gA + (s) * 64, wA + (((s) & 1) ? 512 : 0));\
    }

    STAGE(0);
    for (int s = 0; s < 16; ++s) {
        if (s < 15) {
            STAGE(s + 1);
            asm volatile("s_waitcnt vmcnt(3)" ::: "memory");   // s's 3 landed
        } else {
            asm volatile("s_waitcnt vmcnt(0)" ::: "memory");
        }
        __builtin_amdgcn_s_barrier();      // raw: s+1's loads stay in flight
        const float* Bb = Bs + ((s & 1) ? 4096 : 0);
        const float* Aw = As + wave * 256 + ((s & 1) ? 128 : 0);
#pragma unroll
        for (int dd = 0; dd < 16; dd += 4) {
            float4 a[8];
#pragma unroll
            for (int i = 0; i < 8; ++i)
                a[i] = *(const float4*)(Aw + i * 16 + dd);     // broadcast read
            float4 b[4];
            const int cb = dd ^ bsw;
#pragma unroll
            for (int j = 0; j < 4; ++j)
                b[j] = *(const float4*)&Bb[(l + j * 64) * 16 + cb];
#pragma unroll
            for (int i = 0; i < 8; ++i)
#pragma unroll
                for (int j = 0; j < 4; ++j) {
                    acc[i][j] = fmaf(a[i].x, b[j].x, acc[i][j]);
                    acc[i][j] = fmaf(a[i].y, b[j].y, acc[i][j]);
                    acc[i][j] = fmaf(a[i].z, b[j].z, acc[i][j]);
                    acc[i][j] = fmaf(a[i].w, b[j].w, acc[i][j]);
                }
        }
        __builtin_amdgcn_s_barrier();      // all waves done reading half s&1
    }

    // ---- epilogue: distances + dual argmin (r13-proven) ----
    float c2k[4];
#pragma unroll
    for (int j = 0; j < 4; ++j) c2k[j] = c2[kbase + l + j * 64];
    u64 cbj[4];
#pragma unroll
    for (int j = 0; j < 4; ++j) cbj[j] = ~0ULL;

#pragma unroll
    for (int i = 0; i < 8; ++i) {
        const int row = rowbase + wave * 8 + i;
        const float f2r = f2[row];
        u64 rb = ~0ULL;
#pragma unroll
        for (int j = 0; j < 4; ++j) {
            const float dj = (f2r - 2.0f * acc[i][j]) + c2k[j];
            const u64 kk = ((u64)fkey(dj) << 32) | (u32)(kbase + l + j * 64);
            rb = u64min(rb, kk);
            cbj[j] = u64min(cbj[j], ((u64)fkey(dj) << 32) | (u32)row);
        }
        // full-wave reduce (row is wave-uniform)
        rb = u64min(rb, shflxor64(rb, 1));
        rb = u64min(rb, shflxor64(rb, 2));
        rb = u64min(rb, shflxor64(rb, 4));
        rb = u64min(rb, shflxor64(rb, 8));
        rb = u64min(rb, shflxor64(rb, 16));
        rb = u64min(rb, shflxor64(rb, 32));
        if (l == 0) atomicMin(&rowmin[row], rb);
    }

    // col side: colred aliased onto dead Bs (all reads done at final barrier)
    u64* colred = (u64*)Bs;                // [8][256] u64 = 16 KB <= 32 KB
    __syncthreads();
#pragma unroll
    for (int j = 0; j < 4; ++j) colred[wave * 256 + j * 64 + l] = cbj[j];
    __syncthreads();
    if (t < 256) {
        u64 m = colred[t];
#pragma unroll
        for (int w = 1; w < 8; ++w) m = u64min(m, colred[w * 256 + t]);
        atomicMin(&colmin[kbase + t], m);
    }
}

// Per-token: out_features, assign, commitment partials, counts, feat_sum scatter
__global__ __launch_bounds__(256)
void k_token(const float* __restrict__ F, const float* __restrict__ CB,
             const u64* __restrict__ rowmin, const void* __restrict__ mp,
             const int* __restrict__ flagp,
             float* __restrict__ out_feat, float* __restrict__ out_assign,
             float* __restrict__ cnt, float* __restrict__ fsum,
             float* __restrict__ cpart) {
    __shared__ float red[4];
    const int n = blockIdx.x, d = threadIdx.x;
    const int k = (int)(u32)(rowmin[n] & 0xFFFFFFFFULL);
    const float f = F[(size_t)n * DIM + d];
    const float cv = CB[(size_t)k * DIM + d];
    out_feat[(size_t)n * DIM + d] = (cv + f) - f;   // mirror STE rounding
    const float df = cv - f;
    float s = df * df;
#pragma unroll
    for (int m = 32; m > 0; m >>= 1) s += __shfl_xor(s, m, 64);
    if ((d & 63) == 0) red[d >> 6] = s;
    __syncthreads();
    atomicAdd(&fsum[(size_t)k * DIM + d], f);       // unmasked, as in source
    if (d == 0) {
        out_assign[n] = (float)k;
        bool msk = read_mask(mp, *flagp, n);
        if (msk) {
            float tot = red[0] + red[1] + red[2] + red[3];
            atomicAdd(&cnt[k], 1.0f);
            atomicAdd(&cpart[n & 255], tot * (1.0f / 256.0f));
        }
    }
}

// total, commitment_loss, unassigned_percent
__global__ __launch_bounds__(256)
void k_scalars(const float* __restrict__ cnt, const float* __restrict__ cpart,
               float* __restrict__ totf, float* __restrict__ out) {
    __shared__ float redf[4], redc[4];
    __shared__ int redi[4];
    const int t = threadIdx.x;
    float ts = 0.0f;
    int asg = 0;
    for (int i = t; i < KCB; i += 256) {
        float v = cnt[i];
        ts += v;
        asg += (v > 0.0f) ? 1 : 0;
    }
    float cs = cpart[t];
#pragma unroll
    for (int m = 32; m > 0; m >>= 1) {
        ts += __shfl_xor(ts, m, 64);
        cs += __shfl_xor(cs, m, 64);
        asg += __shfl_xor(asg, m, 64);
    }
    if ((t & 63) == 0) { redf[t >> 6] = ts; redc[t >> 6] = cs; redi[t >> 6] = asg; }
    __syncthreads();
    if (t == 0) {
        float total = redf[0] + redf[1] + redf[2] + redf[3];
        total = fmaxf(total, 1.0f);
        float closs = (redc[0] + redc[1] + redc[2] + redc[3]) / total;
        int a = redi[0] + redi[1] + redi[2] + redi[3];
        totf[0] = total;
        out[OUT_CLOSS] = closs;
        out[OUT_UPCT] = (float)a / 4096.0f;
    }
}

// Codebook EMA update; fsum aliases out_cb (read-then-write per element)
__global__ __launch_bounds__(256)
void k_cbupd(const float* __restrict__ F, const float* __restrict__ CB,
             const float* __restrict__ cnt_in, const float* __restrict__ avg_in,
             const float* __restrict__ ac_, const float* __restrict__ fsum,
             const u64* __restrict__ colmin, const float* __restrict__ totf,
             float* __restrict__ out_count, float* __restrict__ out_avg,
             float* __restrict__ out_cb) {
    const int k = blockIdx.x, d = threadIdx.x;
    const float ac = ac_[k];
    const float total = totf[0];
    const float cn = C_1MG * ac + 0.99f * cnt_in[k];
    const float av = (C_1MG * ac) / total + 0.99f * avg_in[k];
    const float arg = ((-av * 4096.0f) * 10.0f) / C_1MG - 0.001f;
    const float alpha = expf(arg);
    const int tok = (int)(u32)(colmin[k] & 0xFFFFFFFFULL);
    const float cb = CB[(size_t)k * DIM + d];
    const float fs = fsum[(size_t)k * DIM + d];
    const float fr = F[(size_t)tok * DIM + d];
    const float assigned = (0.99f * cb + C_1MG * fs) / fmaxf(cn, 1.0f);
    const float unass = (1.0f - alpha) * cb + alpha * fr;
    const float nc = (ac < 1.0f) ? assigned : unass;   // reference's where()
    out_cb[(size_t)k * DIM + d] = cb + (cb - nc);      // prev + (prev - new)
    if (d == 0) { out_count[k] = cn; out_avg[k] = av; }
}

extern "C" void kernel_launch(void* const* d_in, const int* in_sizes, int n_in,
                              void* d_out, int out_size, void* d_ws, size_t ws_size,
                              hipStream_t stream) {
    const float* F   = (const float*)d_in[0];
    const void*  Mp  = d_in[1];
    const float* CB  = (const float*)d_in[2];
    const float* CNT = (const float*)d_in[3];
    const float* AVG = (const float*)d_in[4];
    float* out = (float*)d_out;
    char* ws = (char*)d_ws;
    if (ws_size < (size_t)WS_END) return;

    u64*   rowmin = (u64*)(ws + WS_ROWMIN);
    u64*   colmin = (u64*)(ws + WS_COLMIN);
    float* cnt    = (float*)(ws + WS_CNT);
    float* cpart  = (float*)(ws + WS_CPART);
    float* totf   = (float*)(ws + WS_TOTAL);
    int*   flag   = (int*)(ws + WS_FLAG);
    float* f2     = (float*)(ws + WS_F2);
    float* c2     = (float*)(ws + WS_C2);
    float* fsum   = out + OUT_CB;   // scratch in the new_codebook output region

    hipMemsetAsync(ws, 0xFF, 163840, stream);                       // rowmin+colmin
    hipMemsetAsync(ws + WS_CNT, 0, WS_FLAG - WS_CNT, stream);       // cnt,cpart,totf
    hipMemsetAsync(fsum, 0, (size_t)KCB * DIM * sizeof(float), stream);

    k_detect<<<1, 64, 0, stream>>>(Mp, flag);
    k_norms<<<N_TOK + KCB, 256, 0, stream>>>(F, CB, Mp, flag, f2, c2);
    k_gemm<<<dim3(256, 16), 512, 0, stream>>>(F, CB, f2, c2, rowmin, colmin);
    k_token<<<N_TOK, 256, 0, stream>>>(F, CB, rowmin, Mp, flag,
                                       out + OUT_FEAT, out + OUT_ASSIGN,
                                       cnt, fsum, cpart);
    k_scalars<<<1, 256, 0, stream>>>(cnt, cpart, totf, out);
    k_cbupd<<<KCB, 256, 0, stream>>>(F, CB, CNT, AVG, cnt, fsum, colmin, totf,
                                     out + OUT_COUNT, out + OUT_AVG, out + OUT_CB);
}

// Round 17
// 547.869 us; speedup vs baseline: 1.2433x; 1.2433x over previous
//
#include <hip/hip_runtime.h>
#include <math.h>

typedef unsigned long long u64;
typedef unsigned int u32;

#define N_TOK 16384
#define DIM   256
#define KCB   4096

// ---- workspace layout (bytes) ----
#define WS_ROWMIN   0         // u64[16384] = 131072
#define WS_COLMIN   131072    // u64[4096]  = 32768   (0xFF region: [0,163840))
#define WS_CNT      163840    // float[4096]
#define WS_CPART    180224    // float[256]
#define WS_TOTAL    181248    // float[1]
#define WS_FLAG     181252    // int[1]   (written by detect kernel)
#define WS_F2       181312    // float[16384]
#define WS_C2       246848    // float[4096]
#define WS_END      263232

// ---- d_out layout (float elements) ----
#define OUT_FEAT    0
#define OUT_ASSIGN  4194304
#define OUT_CLOSS   4210688
#define OUT_UPCT    4210689
#define OUT_COUNT   4210690
#define OUT_AVG     4214786
#define OUT_CB      4218882   // also reused as feat_sum scratch (zeroed first)

// (float)(1.0 - 0.99) as jnp computes it (f64 -> f32 weak scalar)
#define C_1MG 0.009999999776482582f

__device__ __forceinline__ u32 fkey(float d) {
    u32 u = __float_as_uint(d);
    return (u & 0x80000000u) ? ~u : (u | 0x80000000u);
}
__device__ __forceinline__ u64 u64min(u64 a, u64 b) { return a < b ? a : b; }
__device__ __forceinline__ u64 shflxor64(u64 v, int m) {
    int lo = __shfl_xor((int)(u32)(v & 0xFFFFFFFFULL), m, 64);
    int hi = __shfl_xor((int)(u32)(v >> 32), m, 64);
    return ((u64)(u32)hi << 32) | (u32)lo;
}
__device__ __forceinline__ bool read_mask(const void* mp, int flag, int n) {
    if (flag == 2) return ((const float*)mp)[n] != 0.0f;
    if (flag == 1) return ((const int*)mp)[n] != 0;
    return ((const unsigned char*)mp)[n] != 0;
}
// async global->LDS, 16B/lane; LDS dest is wave-uniform base (+lane*16 implicit)
__device__ __forceinline__ void gload_lds16(const void* g, void* l) {
    __builtin_amdgcn_global_load_lds((const __attribute__((address_space(1))) void*)g,
                                     (__attribute__((address_space(3))) void*)l,
                                     16, 0, 0);
}

// Detect mask storage layout: 0 = uint8, 1 = int32, 2 = float32
__global__ void k_detect(const void* __restrict__ mp, int* __restrict__ flag) {
    if (threadIdx.x == 0) {
        const u32* w = (const u32*)mp;
        bool allf = true, alli = true, any1 = false;
        for (int i = 0; i < 64; ++i) {
            u32 x = w[i];
            if (x != 0u && x != 0x3F800000u) allf = false;
            if (x == 0x3F800000u) any1 = true;
            if (x > 1u) alli = false;
        }
        *flag = (allf && any1) ? 2 : (alli ? 1 : 0);
    }
}

// f2[n] = mask ? ||f_n||^2 : +inf ;  c2[k] = ||c_k||^2
__global__ __launch_bounds__(256)
void k_norms(const float* __restrict__ F, const float* __restrict__ CB,
             const void* __restrict__ mp, const int* __restrict__ flagp,
             float* __restrict__ f2, float* __restrict__ c2) {
    __shared__ float red[4];
    const int b = blockIdx.x, d = threadIdx.x;
    const float* src = (b < N_TOK) ? (F + (size_t)b * DIM) : (CB + (size_t)(b - N_TOK) * DIM);
    float v = src[d];
    float s = v * v;
#pragma unroll
    for (int m = 32; m > 0; m >>= 1) s += __shfl_xor(s, m, 64);
    if ((d & 63) == 0) red[d >> 6] = s;
    __syncthreads();
    if (d == 0) {
        float tot = red[0] + red[1] + red[2] + red[3];
        if (b < N_TOK) {
            bool msk = read_mask(mp, *flagp, b);
            f2[b] = msk ? tot : __builtin_huge_valf();
        } else {
            c2[b - N_TOK] = tot;
        }
    }
}

// Fused distance GEMM + dual argmin. Exact fp32 fmaf chain (k-ascending) —
// summation order matches numpy argmin exactly (absmax 0.0, rounds 1/3/9).
// grid (128, 32); block 256; tile 128x128; per-thread 8x8; BD = 32 chunks.
// Staging: pre-swizzled GLOBAL source cols + global_load_lds 16B -> linear LDS.
// LDS image: LDS[r][c] = G[r][c ^ ((r&7)<<2)]. Reads: col dd ^ ((row&7)<<2)
// -> a-reads broadcast (4 addrs/wave, free), b-reads 2-way max (free, m136).
// Empirical optimum after 9 structural probes (r8, r10-r16 all >= this):
// the kernel sits at ~64% of its ds_read-instruction floor (~330us/CU-wide)
// with ~2 resident blocks/CU; exact-argmin blocks MFMA and layout changes.
__global__ __launch_bounds__(256)
void k_gemm(const float* __restrict__ F, const float* __restrict__ CB,
            const float* __restrict__ f2, const float* __restrict__ c2,
            u64* __restrict__ rowmin, u64* __restrict__ colmin) {
    __shared__ float As[128 * 32];     // 16 KB, swizzled image
    __shared__ float Bs[128 * 32];     // 16 KB
    __shared__ u64 colred[4][128];     // 4 KB

    const int t = threadIdx.x;
    const int tx = t & 15;             // cols tx + j*16
    const int ty = t >> 4;             // rows ty + i*16
    const int wave = t >> 6;           // 0..3
    const int rowbase = blockIdx.x * 128;
    const int kbase = blockIdx.y * 128;

    float acc[8][8];
#pragma unroll
    for (int i = 0; i < 8; ++i)
#pragma unroll
        for (int j = 0; j < 8; ++j) acc[i][j] = 0.0f;

    // staging source pointers (4 gload per matrix per chunk)
    const char* gA[4];
    const char* gB[4];
#pragma unroll
    for (int p = 0; p < 4; ++p) {
        const int idx = p * 256 + t;           // 0..1023
        const int r = idx >> 3;                // 8 float4 per 32-float row
        const int c4 = (idx & 7) << 2;
        const int sc = c4 ^ ((r & 7) << 2);    // source col pre-swizzle
        gA[p] = (const char*)(F + (size_t)(rowbase + r) * DIM + sc);
        gB[p] = (const char*)(CB + (size_t)(kbase + r) * DIM + sc);
    }
    char* AsB = (char*)As;
    char* BsB = (char*)Bs;
    const int aswz = (ty & 7) << 2;            // row&7 == ty&7 (i*16 % 8 == 0)
    const int bswz = (tx & 7) << 2;

    for (int ch = 0; ch < 8; ++ch) {
#pragma unroll
        for (int p = 0; p < 4; ++p) {
            const int ldsb = p * 4096 + wave * 1024;   // + lane*16 implicit
            gload_lds16(gA[p] + ch * 128, AsB + ldsb);
            gload_lds16(gB[p] + ch * 128, BsB + ldsb);
        }
        __syncthreads();   // drains vmcnt(0): LDS image complete
#pragma unroll
        for (int dd = 0; dd < 32; dd += 4) {
            const int ca = dd ^ aswz, cb = dd ^ bswz;
            float4 a[8], b[8];
#pragma unroll
            for (int i = 0; i < 8; ++i)
                a[i] = *(const float4*)&As[(ty + i * 16) * 32 + ca];
#pragma unroll
            for (int j = 0; j < 8; ++j)
                b[j] = *(const float4*)&Bs[(tx + j * 16) * 32 + cb];
#pragma unroll
            for (int i = 0; i < 8; ++i)
#pragma unroll
                for (int j = 0; j < 8; ++j) {
                    acc[i][j] = fmaf(a[i].x, b[j].x, acc[i][j]);
                    acc[i][j] = fmaf(a[i].y, b[j].y, acc[i][j]);
                    acc[i][j] = fmaf(a[i].z, b[j].z, acc[i][j]);
                    acc[i][j] = fmaf(a[i].w, b[j].w, acc[i][j]);
                }
        }
        __syncthreads();   // all reads done before next chunk's DMA overwrites
    }

    // ---- epilogue: distances + dual argmin ----
    float c2k[8];
#pragma unroll
    for (int j = 0; j < 8; ++j) c2k[j] = c2[kbase + tx + j * 16];
    u64 cbst[8];
#pragma unroll
    for (int j = 0; j < 8; ++j) cbst[j] = ~0ULL;

#pragma unroll
    for (int i = 0; i < 8; ++i) {
        const int row = rowbase + ty + i * 16;
        const float f2r = f2[row];
        u64 rbst = ~0ULL;
#pragma unroll
        for (int j = 0; j < 8; ++j) {
            float dist = (f2r - 2.0f * acc[i][j]) + c2k[j];
            u64 hk = (u64)fkey(dist) << 32;
            rbst    = u64min(rbst, hk | (u32)(kbase + tx + j * 16));
            cbst[j] = u64min(cbst[j], hk | (u32)row);
        }
        // row reduce across tx (lane bits 0..3)
        rbst = u64min(rbst, shflxor64(rbst, 1));
        rbst = u64min(rbst, shflxor64(rbst, 2));
        rbst = u64min(rbst, shflxor64(rbst, 4));
        rbst = u64min(rbst, shflxor64(rbst, 8));
        if (tx == 0) atomicMin(&rowmin[row], rbst);
    }

    // column reduce: across ty within wave (lane bits 4,5), then across 4 waves
#pragma unroll
    for (int j = 0; j < 8; ++j) {
        cbst[j] = u64min(cbst[j], shflxor64(cbst[j], 16));
        cbst[j] = u64min(cbst[j], shflxor64(cbst[j], 32));
    }
    if ((t & 63) < 16) {
#pragma unroll
        for (int j = 0; j < 8; ++j) colred[wave][tx + j * 16] = cbst[j];
    }
    __syncthreads();
    if (t < 128) {
        u64 m = u64min(u64min(colred[0][t], colred[1][t]),
                       u64min(colred[2][t], colred[3][t]));
        atomicMin(&colmin[kbase + t], m);
    }
}

// Per-token: out_features, assign, commitment partials, counts, feat_sum scatter
__global__ __launch_bounds__(256)
void k_token(const float* __restrict__ F, const float* __restrict__ CB,
             const u64* __restrict__ rowmin, const void* __restrict__ mp,
             const int* __restrict__ flagp,
             float* __restrict__ out_feat, float* __restrict__ out_assign,
             float* __restrict__ cnt, float* __restrict__ fsum,
             float* __restrict__ cpart) {
    __shared__ float red[4];
    const int n = blockIdx.x, d = threadIdx.x;
    const int k = (int)(u32)(rowmin[n] & 0xFFFFFFFFULL);
    const float f = F[(size_t)n * DIM + d];
    const float cv = CB[(size_t)k * DIM + d];
    out_feat[(size_t)n * DIM + d] = (cv + f) - f;   // mirror STE rounding
    const float df = cv - f;
    float s = df * df;
#pragma unroll
    for (int m = 32; m > 0; m >>= 1) s += __shfl_xor(s, m, 64);
    if ((d & 63) == 0) red[d >> 6] = s;
    __syncthreads();
    atomicAdd(&fsum[(size_t)k * DIM + d], f);       // unmasked, as in source
    if (d == 0) {
        out_assign[n] = (float)k;
        bool msk = read_mask(mp, *flagp, n);
        if (msk) {
            float tot = red[0] + red[1] + red[2] + red[3];
            atomicAdd(&cnt[k], 1.0f);
            atomicAdd(&cpart[n & 255], tot * (1.0f / 256.0f));
        }
    }
}

// total, commitment_loss, unassigned_percent
__global__ __launch_bounds__(256)
void k_scalars(const float* __restrict__ cnt, const float* __restrict__ cpart,
               float* __restrict__ totf, float* __restrict__ out) {
    __shared__ float redf[4], redc[4];
    __shared__ int redi[4];
    const int t = threadIdx.x;
    float ts = 0.0f;
    int asg = 0;
    for (int i = t; i < KCB; i += 256) {
        float v = cnt[i];
        ts += v;
        asg += (v > 0.0f) ? 1 : 0;
    }
    float cs = cpart[t];
#pragma unroll
    for (int m = 32; m > 0; m >>= 1) {
        ts += __shfl_xor(ts, m, 64);
        cs += __shfl_xor(cs, m, 64);
        asg += __shfl_xor(asg, m, 64);
    }
    if ((t & 63) == 0) { redf[t >> 6] = ts; redc[t >> 6] = cs; redi[t >> 6] = asg; }
    __syncthreads();
    if (t == 0) {
        float total = redf[0] + redf[1] + redf[2] + redf[3];
        total = fmaxf(total, 1.0f);
        float closs = (redc[0] + redc[1] + redc[2] + redc[3]) / total;
        int a = redi[0] + redi[1] + redi[2] + redi[3];
        totf[0] = total;
        out[OUT_CLOSS] = closs;
        out[OUT_UPCT] = (float)a / 4096.0f;
    }
}

// Codebook EMA update; fsum aliases out_cb (read-then-write per element)
__global__ __launch_bounds__(256)
void k_cbupd(const float* __restrict__ F, const float* __restrict__ CB,
             const float* __restrict__ cnt_in, const float* __restrict__ avg_in,
             const float* __restrict__ ac_, const float* __restrict__ fsum,
             const u64* __restrict__ colmin, const float* __restrict__ totf,
             float* __restrict__ out_count, float* __restrict__ out_avg,
             float* __restrict__ out_cb) {
    const int k = blockIdx.x, d = threadIdx.x;
    const float ac = ac_[k];
    const float total = totf[0];
    const float cn = C_1MG * ac + 0.99f * cnt_in[k];
    const float av = (C_1MG * ac) / total + 0.99f * avg_in[k];
    const float arg = ((-av * 4096.0f) * 10.0f) / C_1MG - 0.001f;
    const float alpha = expf(arg);
    const int tok = (int)(u32)(colmin[k] & 0xFFFFFFFFULL);
    const float cb = CB[(size_t)k * DIM + d];
    const float fs = fsum[(size_t)k * DIM + d];
    const float fr = F[(size_t)tok * DIM + d];
    const float assigned = (0.99f * cb + C_1MG * fs) / fmaxf(cn, 1.0f);
    const float unass = (1.0f - alpha) * cb + alpha * fr;
    const float nc = (ac < 1.0f) ? assigned : unass;   // reference's where()
    out_cb[(size_t)k * DIM + d] = cb + (cb - nc);      // prev + (prev - new)
    if (d == 0) { out_count[k] = cn; out_avg[k] = av; }
}

extern "C" void kernel_launch(void* const* d_in, const int* in_sizes, int n_in,
                              void* d_out, int out_size, void* d_ws, size_t ws_size,
                              hipStream_t stream) {
    const float* F   = (const float*)d_in[0];
    const void*  Mp  = d_in[1];
    const float* CB  = (const float*)d_in[2];
    const float* CNT = (const float*)d_in[3];
    const float* AVG = (const float*)d_in[4];
    float* out = (float*)d_out;
    char* ws = (char*)d_ws;
    if (ws_size < (size_t)WS_END) return;

    u64*   rowmin = (u64*)(ws + WS_ROWMIN);
    u64*   colmin = (u64*)(ws + WS_COLMIN);
    float* cnt    = (float*)(ws + WS_CNT);
    float* cpart  = (float*)(ws + WS_CPART);
    float* totf   = (float*)(ws + WS_TOTAL);
    int*   flag   = (int*)(ws + WS_FLAG);
    float* f2     = (float*)(ws + WS_F2);
    float* c2     = (float*)(ws + WS_C2);
    float* fsum   = out + OUT_CB;   // scratch in the new_codebook output region

    hipMemsetAsync(ws, 0xFF, 163840, stream);                       // rowmin+colmin
    hipMemsetAsync(ws + WS_CNT, 0, WS_FLAG - WS_CNT, stream);       // cnt,cpart,totf
    hipMemsetAsync(fsum, 0, (size_t)KCB * DIM * sizeof(float), stream);

    k_detect<<<1, 64, 0, stream>>>(Mp, flag);
    k_norms<<<N_TOK + KCB, 256, 0, stream>>>(F, CB, Mp, flag, f2, c2);
    k_gemm<<<dim3(128, 32), 256, 0, stream>>>(F, CB, f2, c2, rowmin, colmin);
    k_token<<<N_TOK, 256, 0, stream>>>(F, CB, rowmin, Mp, flag,
                                       out + OUT_FEAT, out + OUT_ASSIGN,
                                       cnt, fsum, cpart);
    k_scalars<<<1, 256, 0, stream>>>(cnt, cpart, totf, out);
    k_cbupd<<<KCB, 256, 0, stream>>>(F, CB, CNT, AVG, cnt, fsum, colmin, totf,
                                     out + OUT_COUNT, out + OUT_AVG, out + OUT_CB);
}